// Round 1
// baseline (236.284 us; speedup 1.0000x reference)
//
#include <hip/hip_runtime.h>
#include <hip/hip_bf16.h>

// Problem constants (fixed by setup_inputs)
#define BQ_TOTAL 4800          // B*NQ = 16*300
#define D_MODEL 256
#define N_HEADS 8
#define SUM_POINTS 16
#define HEAD_DIM 32
#define SEQ 8500
#define OUT_ELEMS (BQ_TOTAL * D_MODEL)      // 1228800
#define ATTN_ELEMS (BQ_TOTAL * N_HEADS * SUM_POINTS)  // 614400

// ---------------- Kernel 1: logits GEMM ----------------
// C(4800 x 384) = hs(4800 x 256) @ [w_off; w_attn]^T + bias
// cols [0,256) -> off logits to ws (row-major 4800x256)
// cols [256,384) -> attn logits to d_out attn region (row-major 4800x128)
#define BM 64
#define BN 64
#define BK 32
#define PAD 4

__global__ __launch_bounds__(256) void gemm_logits(
    const float* __restrict__ hs,
    const float* __restrict__ w_off, const float* __restrict__ b_off,
    const float* __restrict__ w_attn, const float* __restrict__ b_attn,
    float* __restrict__ off_out, float* __restrict__ attn_out)
{
    __shared__ float As[BK][BM + PAD];   // k-major
    __shared__ float Bs[BK][BN + PAD];

    const int tid = threadIdx.x;
    const int row0 = blockIdx.x * BM;     // query rows
    const int col0 = blockIdx.y * BN;     // output cols in [0,384)

    const float* Bsrc; const float* bias; int bcol;
    if (col0 < 256) { Bsrc = w_off;  bias = b_off;  bcol = col0; }
    else            { Bsrc = w_attn; bias = b_attn; bcol = col0 - 256; }

    const int tx = tid & 15;          // 0..15 -> 4 cols each
    const int ty = tid >> 4;          // 0..15 -> 4 rows each
    const int lrow = tid >> 3;        // 0..31 (load row)
    const int k4 = (tid & 7) * 4;     // 0,4,..,28 (load k offset)

    float acc[4][4] = {};

    for (int k0 = 0; k0 < 256; k0 += BK) {
        #pragma unroll
        for (int rr = 0; rr < 2; rr++) {
            const int r = lrow + rr * 32;
            const float4 a = *(const float4*)(hs + (size_t)(row0 + r) * 256 + k0 + k4);
            As[k4 + 0][r] = a.x; As[k4 + 1][r] = a.y;
            As[k4 + 2][r] = a.z; As[k4 + 3][r] = a.w;
            const float4 b = *(const float4*)(Bsrc + (size_t)(bcol + r) * 256 + k0 + k4);
            Bs[k4 + 0][r] = b.x; Bs[k4 + 1][r] = b.y;
            Bs[k4 + 2][r] = b.z; Bs[k4 + 3][r] = b.w;
        }
        __syncthreads();
        #pragma unroll
        for (int kk = 0; kk < BK; kk++) {
            const float4 av = *(const float4*)&As[kk][ty * 4];
            const float4 bv = *(const float4*)&Bs[kk][tx * 4];
            const float af[4] = {av.x, av.y, av.z, av.w};
            const float bf[4] = {bv.x, bv.y, bv.z, bv.w};
            #pragma unroll
            for (int i = 0; i < 4; i++)
                #pragma unroll
                for (int j = 0; j < 4; j++)
                    acc[i][j] += af[i] * bf[j];
        }
        __syncthreads();
    }

    // epilogue: add bias, store as float4 per row
    #pragma unroll
    for (int i = 0; i < 4; i++) {
        const int r = row0 + ty * 4 + i;
        const int c_local = tx * 4;         // within [0,BN)
        float4 v;
        v.x = acc[i][0] + bias[bcol + c_local + 0];
        v.y = acc[i][1] + bias[bcol + c_local + 1];
        v.z = acc[i][2] + bias[bcol + c_local + 2];
        v.w = acc[i][3] + bias[bcol + c_local + 3];
        if (col0 < 256)
            *(float4*)(off_out + (size_t)r * 256 + col0 + c_local) = v;
        else
            *(float4*)(attn_out + (size_t)r * 128 + (col0 - 256) + c_local) = v;
    }
}

// ---------------- Kernel 2: softmax + deformable sampling ----------------
// One wave per (b,q,h). 4 waves / 256-thread block. 38400 items -> 9600 blocks.
__global__ __launch_bounds__(256) void deform_sample(
    const float* __restrict__ enc,      // (16, 8500, 256)
    const float* __restrict__ refp,     // (4800, 4)
    const float* __restrict__ offlog,   // ws (4800, 256)
    float* __restrict__ attn,           // (4800, 128): logits in -> probs out
    float* __restrict__ out)            // (4800, 256)
{
    __shared__ float probs[4][16];
    __shared__ float offs[4][32];

    const int tid = threadIdx.x;
    const int w = tid >> 6;        // wave 0..3
    const int lane = tid & 63;
    const int item = blockIdx.x * 4 + w;   // 0..38399
    const int bq = item >> 3;              // b*300+q
    const int h = item & 7;

    // --- softmax over the 16 attn logits (lanes 0..15 cooperate) ---
    float* attn_ptr = attn + (size_t)bq * 128 + h * 16;
    if (lane < 16) {
        const float l = attn_ptr[lane];
        float m = l;
        #pragma unroll
        for (int s = 1; s < 16; s <<= 1) m = fmaxf(m, __shfl_xor(m, s, 16));
        const float e = __expf(l - m);
        float ssum = e;
        #pragma unroll
        for (int s = 1; s < 16; s <<= 1) ssum += __shfl_xor(ssum, s, 16);
        const float p = e / ssum;
        attn_ptr[lane] = p;        // second output
        probs[w][lane] = p;
    }
    if (lane < 32) {
        offs[w][lane] = offlog[(size_t)bq * 256 + h * 32 + lane];
    }
    const float* rp = refp + (size_t)bq * 4;
    const float cx = rp[0], cy = rp[1], rw = rp[2], rh = rp[3];
    __syncthreads();

    // --- sampling: channel = lane&31, half-waves take alternating points ---
    const int c = lane & 31;
    const int half = lane >> 5;
    const int b = bq / 300;
    const float* encb = enc + ((size_t)b * SEQ) * 256 + h * 32 + c;

    const int   Wl_[4]   = {80, 40, 20, 10};
    const int   base_[4] = {0, 6400, 8000, 8400};

    float acc = 0.f;
    #pragma unroll
    for (int p8 = 0; p8 < 8; p8++) {
        const int p = p8 * 2 + half;
        const int lvl = p >> 2;
        const int Wl = Wl_[lvl];         // levels are square: Hl == Wl
        const int base = base_[lvl];

        const float a  = probs[w][p];
        const float ox = offs[w][2 * p];
        const float oy = offs[w][2 * p + 1];
        // offset = off * (1/P=0.25) * ref_wh * 0.5  -> 0.125
        const float lx = cx + ox * 0.125f * rw;
        const float ly = cy + oy * 0.125f * rh;
        // grid = 2*loc-1; img coord = (g+1)*W/2-0.5 = loc*W - 0.5
        const float gx = lx * (float)Wl - 0.5f;
        const float gy = ly * (float)Wl - 0.5f;
        const float x0f = floorf(gx), y0f = floorf(gy);
        const float fx = gx - x0f, fy = gy - y0f;
        const int x0 = (int)x0f, y0 = (int)y0f;

        const bool xv0 = (x0 >= 0) && (x0 < Wl);
        const bool xv1 = (x0 + 1 >= 0) && (x0 + 1 < Wl);
        const bool yv0 = (y0 >= 0) && (y0 < Wl);
        const bool yv1 = (y0 + 1 >= 0) && (y0 + 1 < Wl);

        float v00 = 0.f, v01 = 0.f, v10 = 0.f, v11 = 0.f;
        const float* rowp0 = encb + (size_t)(base + y0 * Wl) * 256;
        if (yv0) {
            if (xv0) v00 = rowp0[(size_t)x0 * 256];
            if (xv1) v01 = rowp0[(size_t)(x0 + 1) * 256];
        }
        if (yv1) {
            const float* rowp1 = rowp0 + (size_t)Wl * 256;
            if (xv0) v10 = rowp1[(size_t)x0 * 256];
            if (xv1) v11 = rowp1[(size_t)(x0 + 1) * 256];
        }
        const float top = v00 + (v01 - v00) * fx;
        const float bot = v10 + (v11 - v10) * fx;
        acc += a * (top + (bot - top) * fy);
    }
    // combine the two half-wave partials (even/odd points, same channel)
    acc += __shfl_xor(acc, 32);
    if (half == 0) {
        out[(size_t)bq * 256 + h * 32 + c] = acc;
    }
}

extern "C" void kernel_launch(void* const* d_in, const int* in_sizes, int n_in,
                              void* d_out, int out_size, void* d_ws, size_t ws_size,
                              hipStream_t stream) {
    const float* hs     = (const float*)d_in[0];   // (16,300,256)
    const float* enc    = (const float*)d_in[1];   // (16,8500,256)
    const float* refp   = (const float*)d_in[2];   // (16,300,1,4)
    // d_in[3] = spatial_shapes (int64) — static, hardcoded
    const float* w_off  = (const float*)d_in[4];   // (256,256)
    const float* b_off  = (const float*)d_in[5];   // (256,)
    const float* w_attn = (const float*)d_in[6];   // (128,256)
    const float* b_attn = (const float*)d_in[7];   // (128,)

    float* out  = (float*)d_out;            // (16,300,256)
    float* attn = out + OUT_ELEMS;          // (16,300,8,16)
    float* offlog = (float*)d_ws;           // (4800,256) fp32 = 4.9 MB

    dim3 g1(BQ_TOTAL / BM, 384 / BN);       // (75, 6)
    gemm_logits<<<g1, 256, 0, stream>>>(hs, w_off, b_off, w_attn, b_attn, offlog, attn);

    deform_sample<<<(BQ_TOTAL * N_HEADS) / 4, 256, 0, stream>>>(enc, refp, offlog, attn, out);
}

// Round 2
// 231.446 us; speedup vs baseline: 1.0209x; 1.0209x over previous
//
#include <hip/hip_runtime.h>
#include <hip/hip_bf16.h>

// Problem constants (fixed by setup_inputs)
#define BQ_TOTAL 4800          // B*NQ = 16*300
#define D_MODEL 256
#define N_HEADS 8
#define SUM_POINTS 16
#define HEAD_DIM 32
#define SEQ 8500
#define OUT_ELEMS (BQ_TOTAL * D_MODEL)      // 1228800

// ---------------- Kernel 1: logits GEMM (unchanged from R1) ----------------
#define BM 64
#define BN 64
#define BK 32
#define PAD 4

__global__ __launch_bounds__(256) void gemm_logits(
    const float* __restrict__ hs,
    const float* __restrict__ w_off, const float* __restrict__ b_off,
    const float* __restrict__ w_attn, const float* __restrict__ b_attn,
    float* __restrict__ off_out, float* __restrict__ attn_out)
{
    __shared__ float As[BK][BM + PAD];   // k-major
    __shared__ float Bs[BK][BN + PAD];

    const int tid = threadIdx.x;
    const int row0 = blockIdx.x * BM;
    const int col0 = blockIdx.y * BN;

    const float* Bsrc; const float* bias; int bcol;
    if (col0 < 256) { Bsrc = w_off;  bias = b_off;  bcol = col0; }
    else            { Bsrc = w_attn; bias = b_attn; bcol = col0 - 256; }

    const int tx = tid & 15;
    const int ty = tid >> 4;
    const int lrow = tid >> 3;
    const int k4 = (tid & 7) * 4;

    float acc[4][4] = {};

    for (int k0 = 0; k0 < 256; k0 += BK) {
        #pragma unroll
        for (int rr = 0; rr < 2; rr++) {
            const int r = lrow + rr * 32;
            const float4 a = *(const float4*)(hs + (size_t)(row0 + r) * 256 + k0 + k4);
            As[k4 + 0][r] = a.x; As[k4 + 1][r] = a.y;
            As[k4 + 2][r] = a.z; As[k4 + 3][r] = a.w;
            const float4 b = *(const float4*)(Bsrc + (size_t)(bcol + r) * 256 + k0 + k4);
            Bs[k4 + 0][r] = b.x; Bs[k4 + 1][r] = b.y;
            Bs[k4 + 2][r] = b.z; Bs[k4 + 3][r] = b.w;
        }
        __syncthreads();
        #pragma unroll
        for (int kk = 0; kk < BK; kk++) {
            const float4 av = *(const float4*)&As[kk][ty * 4];
            const float4 bv = *(const float4*)&Bs[kk][tx * 4];
            const float af[4] = {av.x, av.y, av.z, av.w};
            const float bf[4] = {bv.x, bv.y, bv.z, bv.w};
            #pragma unroll
            for (int i = 0; i < 4; i++)
                #pragma unroll
                for (int j = 0; j < 4; j++)
                    acc[i][j] += af[i] * bf[j];
        }
        __syncthreads();
    }

    #pragma unroll
    for (int i = 0; i < 4; i++) {
        const int r = row0 + ty * 4 + i;
        const int c_local = tx * 4;
        float4 v;
        v.x = acc[i][0] + bias[bcol + c_local + 0];
        v.y = acc[i][1] + bias[bcol + c_local + 1];
        v.z = acc[i][2] + bias[bcol + c_local + 2];
        v.w = acc[i][3] + bias[bcol + c_local + 3];
        if (col0 < 256)
            *(float4*)(off_out + (size_t)r * 256 + col0 + c_local) = v;
        else
            *(float4*)(attn_out + (size_t)r * 128 + (col0 - 256) + c_local) = v;
    }
}

// ---------------- Kernel 2: softmax + deformable sampling (v2) ----------------
// One wave per (b,q,h). Lane -> (point p = lane>>2, sub = lane&3).
// Each lane: 8 channels of one point via 2x float4 loads per corner.
// No LDS, no __syncthreads; all cross-lane via __shfl_xor.
__global__ __launch_bounds__(256) void deform_sample(
    const float* __restrict__ enc,      // (16, 8500, 256)
    const float* __restrict__ refp,     // (4800, 4)
    const float* __restrict__ offlog,   // ws (4800, 256)
    float* __restrict__ attn,           // (4800, 128): logits in -> probs out
    float* __restrict__ out)            // (4800, 256)
{
    const int tid = threadIdx.x;
    const int w = tid >> 6;
    const int lane = tid & 63;
    const int item = blockIdx.x * 4 + w;   // 0..38399
    const int bq = item >> 3;              // b*300+q
    const int h = item & 7;
    const int p = lane >> 2;               // point 0..15
    const int sub = lane & 3;              // channel subgroup

    // --- softmax over 16 points, wave-wide (xor strides 4..32 permute p) ---
    float* attn_ptr = attn + (size_t)bq * 128 + h * 16;
    const float l = attn_ptr[p];
    float m = l;
    #pragma unroll
    for (int s = 4; s < 64; s <<= 1) m = fmaxf(m, __shfl_xor(m, s));
    const float e = __expf(l - m);
    float ssum = e;
    #pragma unroll
    for (int s = 4; s < 64; s <<= 1) ssum += __shfl_xor(ssum, s);
    const float prob = e / ssum;
    if (sub == 0) attn_ptr[p] = prob;      // second output

    // --- per-point sampling location ---
    const float2 off2 = *(const float2*)(offlog + (size_t)bq * 256 + h * 32 + 2 * p);
    const float* rp = refp + (size_t)bq * 4;
    const float cx = rp[0], cy = rp[1], rw = rp[2], rh = rp[3];

    const int lvl = p >> 2;
    const int Wl = 80 >> lvl;              // square levels
    int base = 0;
    if (lvl == 1) base = 6400;
    else if (lvl == 2) base = 8000;
    else if (lvl == 3) base = 8400;

    const float Wf = (float)Wl;
    // offset = logit * (1/P=0.25) * ref_wh * OFFSET_SCALE(0.5) = logit * 0.125 * wh
    const float gx = (cx + off2.x * 0.125f * rw) * Wf - 0.5f;
    const float gy = (cy + off2.y * 0.125f * rh) * Wf - 0.5f;
    const float x0f = floorf(gx), y0f = floorf(gy);
    const float fx = gx - x0f, fy = gy - y0f;
    const int x0 = (int)x0f, y0 = (int)y0f;

    const int b = bq / 300;
    const float* pbase = enc + ((size_t)b * SEQ + base) * 256 + h * 32 + sub * 4;

    float4 acc0 = {0.f, 0.f, 0.f, 0.f};
    float4 acc1 = {0.f, 0.f, 0.f, 0.f};
    #pragma unroll
    for (int c = 0; c < 4; c++) {
        const int xc = x0 + (c & 1);
        const int yc = y0 + (c >> 1);
        const float wx = (c & 1) ? fx : (1.0f - fx);
        const float wy = (c >> 1) ? fy : (1.0f - fy);
        const bool valid = (xc >= 0) && (xc < Wl) && (yc >= 0) && (yc < Wl);
        const int xi = min(max(xc, 0), Wl - 1);
        const int yi = min(max(yc, 0), Wl - 1);
        const float wgt = valid ? wx * wy : 0.0f;
        const float* vp = pbase + (size_t)(yi * Wl + xi) * 256;
        const float4 va = *(const float4*)(vp);
        const float4 vb = *(const float4*)(vp + 16);
        acc0.x += wgt * va.x; acc0.y += wgt * va.y;
        acc0.z += wgt * va.z; acc0.w += wgt * va.w;
        acc1.x += wgt * vb.x; acc1.y += wgt * vb.y;
        acc1.z += wgt * vb.z; acc1.w += wgt * vb.w;
    }

    float vals[8];
    vals[0] = acc0.x * prob; vals[1] = acc0.y * prob;
    vals[2] = acc0.z * prob; vals[3] = acc0.w * prob;
    vals[4] = acc1.x * prob; vals[5] = acc1.y * prob;
    vals[6] = acc1.z * prob; vals[7] = acc1.w * prob;

    // reduce over points (lanes differing in bits 2..5)
    #pragma unroll
    for (int s = 4; s < 64; s <<= 1) {
        #pragma unroll
        for (int j = 0; j < 8; j++) vals[j] += __shfl_xor(vals[j], s);
    }

    if (lane < 8) {
        const int halfs = lane >> 2;       // 0: chans [0,16), 1: [16,32)
        const int sb = lane & 3;
        float4 v;
        if (halfs == 0) { v.x = vals[0]; v.y = vals[1]; v.z = vals[2]; v.w = vals[3]; }
        else            { v.x = vals[4]; v.y = vals[5]; v.z = vals[6]; v.w = vals[7]; }
        // note: after reduction all lanes in an xor-class agree; lanes 0..7 cover
        // sub 0..3 x both halves only if sub matches — lanes 4..7 are sub 0..3 of p=1,
        // whose reduced vals equal those of lanes 0..3. We need per-sub values:
        // lane L<8 has sub=(L&3) and holds the reduced result for its own sub. OK.
        out[(size_t)bq * 256 + h * 32 + halfs * 16 + sb * 4 + 0] = v.x;
        out[(size_t)bq * 256 + h * 32 + halfs * 16 + sb * 4 + 1] = v.y;
        out[(size_t)bq * 256 + h * 32 + halfs * 16 + sb * 4 + 2] = v.z;
        out[(size_t)bq * 256 + h * 32 + halfs * 16 + sb * 4 + 3] = v.w;
    }
}

extern "C" void kernel_launch(void* const* d_in, const int* in_sizes, int n_in,
                              void* d_out, int out_size, void* d_ws, size_t ws_size,
                              hipStream_t stream) {
    const float* hs     = (const float*)d_in[0];   // (16,300,256)
    const float* enc    = (const float*)d_in[1];   // (16,8500,256)
    const float* refp   = (const float*)d_in[2];   // (16,300,1,4)
    // d_in[3] = spatial_shapes (int64) — static, hardcoded
    const float* w_off  = (const float*)d_in[4];   // (256,256)
    const float* b_off  = (const float*)d_in[5];   // (256,)
    const float* w_attn = (const float*)d_in[6];   // (128,256)
    const float* b_attn = (const float*)d_in[7];   // (128,)

    float* out  = (float*)d_out;            // (16,300,256)
    float* attn = out + OUT_ELEMS;          // (16,300,8,16)
    float* offlog = (float*)d_ws;           // (4800,256) fp32 = 4.9 MB

    dim3 g1(BQ_TOTAL / BM, 384 / BN);       // (75, 6)
    gemm_logits<<<g1, 256, 0, stream>>>(hs, w_off, b_off, w_attn, b_attn, offlog, attn);

    deform_sample<<<(BQ_TOTAL * N_HEADS) / 4, 256, 0, stream>>>(enc, refp, offlog, attn, out);
}

// Round 3
// 216.944 us; speedup vs baseline: 1.0891x; 1.0668x over previous
//
#include <hip/hip_runtime.h>
#include <hip/hip_bf16.h>

// Problem constants (fixed by setup_inputs)
#define BQ_TOTAL 4800          // B*NQ = 16*300
#define D_MODEL 256
#define N_HEADS 8
#define SUM_POINTS 16
#define HEAD_DIM 32
#define SEQ 8500
#define OUT_ELEMS (BQ_TOTAL * D_MODEL)      // 1228800

typedef _Float16 half8 __attribute__((ext_vector_type(8)));
typedef _Float16 half4 __attribute__((ext_vector_type(4)));
typedef float floatx4 __attribute__((ext_vector_type(4)));

// ---------------- Kernel 1: logits GEMM via f16 MFMA ----------------
// C(4800 x 384) = hs(4800 x 256) @ [w_off; w_attn]^T + bias
// Tile 64x64, full K=256 staged to LDS as f16 once (single barrier).
// Wave w computes rows [w*16, w*16+16) x all 64 cols (4 col-tiles x 8 ksteps).
#define LDK 264   // 256 + 8 f16 pad -> 528 B row stride, 2-way-bank-free b128 reads

__global__ __launch_bounds__(256) void gemm_logits_mfma(
    const float* __restrict__ hs,
    const float* __restrict__ w_off, const float* __restrict__ b_off,
    const float* __restrict__ w_attn, const float* __restrict__ b_attn,
    float* __restrict__ off_out, float* __restrict__ attn_out)
{
    __shared__ _Float16 Asld[64 * LDK];
    __shared__ _Float16 Bsld[64 * LDK];

    const int tid = threadIdx.x;
    const int row0 = blockIdx.x * 64;       // query rows
    const int col0 = blockIdx.y * 64;       // output cols in [0,384)

    const float* Bsrc; const float* bias;
    if (col0 < 256) { Bsrc = w_off  + (size_t)col0 * 256;        bias = b_off  + col0; }
    else            { Bsrc = w_attn + (size_t)(col0 - 256) * 256; bias = b_attn + (col0 - 256); }

    // --- stage A and B tiles (64 x 256 each), fp32 -> f16 convert ---
    #pragma unroll
    for (int i = 0; i < 16; i++) {
        const int idx = tid + i * 256;      // 0..4095
        const int r = idx >> 6;             // 0..63
        const int kc = (idx & 63) << 2;     // 0..252, step 4

        const float4 a = *(const float4*)(hs + (size_t)(row0 + r) * 256 + kc);
        half4 ah; ah[0] = (_Float16)a.x; ah[1] = (_Float16)a.y;
                  ah[2] = (_Float16)a.z; ah[3] = (_Float16)a.w;
        *(half4*)&Asld[r * LDK + kc] = ah;

        const float4 b = *(const float4*)(Bsrc + (size_t)r * 256 + kc);
        half4 bh; bh[0] = (_Float16)b.x; bh[1] = (_Float16)b.y;
                  bh[2] = (_Float16)b.z; bh[3] = (_Float16)b.w;
        *(half4*)&Bsld[r * LDK + kc] = bh;
    }
    __syncthreads();

    // --- MFMA compute: A-frag m=lane&15 (row), k=quad*8+j; B-frag n=lane&15 (col) ---
    const int wv = tid >> 6;
    const int lane = tid & 63;
    const int m = lane & 15;
    const int quad = lane >> 4;

    half8 af[8];
    #pragma unroll
    for (int q8 = 0; q8 < 8; q8++)
        af[q8] = *(const half8*)&Asld[(wv * 16 + m) * LDK + q8 * 32 + quad * 8];

    floatx4 acc[4] = {{0.f,0.f,0.f,0.f},{0.f,0.f,0.f,0.f},{0.f,0.f,0.f,0.f},{0.f,0.f,0.f,0.f}};
    #pragma unroll
    for (int ct = 0; ct < 4; ct++) {
        #pragma unroll
        for (int q8 = 0; q8 < 8; q8++) {
            const half8 bf = *(const half8*)&Bsld[(ct * 16 + m) * LDK + q8 * 32 + quad * 8];
            acc[ct] = __builtin_amdgcn_mfma_f32_16x16x32_f16(af[q8], bf, acc[ct], 0, 0, 0);
        }
    }

    // --- epilogue: C/D layout col=lane&15, row=quad*4+reg; bias in fp32 ---
    #pragma unroll
    for (int ct = 0; ct < 4; ct++) {
        const int col_l = ct * 16 + m;        // 0..63 within tile
        const float bv = bias[col_l];
        #pragma unroll
        for (int rg = 0; rg < 4; rg++) {
            const int row = row0 + wv * 16 + quad * 4 + rg;
            const float v = acc[ct][rg] + bv;
            if (col0 < 256)
                off_out[(size_t)row * 256 + col0 + col_l] = v;
            else
                attn_out[(size_t)row * 128 + (col0 - 256) + col_l] = v;
        }
    }
}

// ---------------- Kernel 2: softmax + deformable sampling (v2, unchanged) ----------------
__global__ __launch_bounds__(256) void deform_sample(
    const float* __restrict__ enc,      // (16, 8500, 256)
    const float* __restrict__ refp,     // (4800, 4)
    const float* __restrict__ offlog,   // ws (4800, 256)
    float* __restrict__ attn,           // (4800, 128): logits in -> probs out
    float* __restrict__ out)            // (4800, 256)
{
    const int tid = threadIdx.x;
    const int w = tid >> 6;
    const int lane = tid & 63;
    const int item = blockIdx.x * 4 + w;   // 0..38399
    const int bq = item >> 3;              // b*300+q
    const int h = item & 7;
    const int p = lane >> 2;               // point 0..15
    const int sub = lane & 3;              // channel subgroup

    // --- softmax over 16 points, wave-wide (xor strides 4..32 permute p) ---
    float* attn_ptr = attn + (size_t)bq * 128 + h * 16;
    const float l = attn_ptr[p];
    float m = l;
    #pragma unroll
    for (int s = 4; s < 64; s <<= 1) m = fmaxf(m, __shfl_xor(m, s));
    const float e = __expf(l - m);
    float ssum = e;
    #pragma unroll
    for (int s = 4; s < 64; s <<= 1) ssum += __shfl_xor(ssum, s);
    const float prob = e / ssum;
    if (sub == 0) attn_ptr[p] = prob;      // second output

    // --- per-point sampling location ---
    const float2 off2 = *(const float2*)(offlog + (size_t)bq * 256 + h * 32 + 2 * p);
    const float* rp = refp + (size_t)bq * 4;
    const float cx = rp[0], cy = rp[1], rw = rp[2], rh = rp[3];

    const int lvl = p >> 2;
    const int Wl = 80 >> lvl;              // square levels
    int base = 0;
    if (lvl == 1) base = 6400;
    else if (lvl == 2) base = 8000;
    else if (lvl == 3) base = 8400;

    const float Wf = (float)Wl;
    // offset = logit * (1/P=0.25) * ref_wh * OFFSET_SCALE(0.5) = logit * 0.125 * wh
    const float gx = (cx + off2.x * 0.125f * rw) * Wf - 0.5f;
    const float gy = (cy + off2.y * 0.125f * rh) * Wf - 0.5f;
    const float x0f = floorf(gx), y0f = floorf(gy);
    const float fx = gx - x0f, fy = gy - y0f;
    const int x0 = (int)x0f, y0 = (int)y0f;

    const int b = bq / 300;
    const float* pbase = enc + ((size_t)b * SEQ + base) * 256 + h * 32 + sub * 4;

    float4 acc0 = {0.f, 0.f, 0.f, 0.f};
    float4 acc1 = {0.f, 0.f, 0.f, 0.f};
    #pragma unroll
    for (int c = 0; c < 4; c++) {
        const int xc = x0 + (c & 1);
        const int yc = y0 + (c >> 1);
        const float wx = (c & 1) ? fx : (1.0f - fx);
        const float wy = (c >> 1) ? fy : (1.0f - fy);
        const bool valid = (xc >= 0) && (xc < Wl) && (yc >= 0) && (yc < Wl);
        const int xi = min(max(xc, 0), Wl - 1);
        const int yi = min(max(yc, 0), Wl - 1);
        const float wgt = valid ? wx * wy : 0.0f;
        const float* vp = pbase + (size_t)(yi * Wl + xi) * 256;
        const float4 va = *(const float4*)(vp);
        const float4 vb = *(const float4*)(vp + 16);
        acc0.x += wgt * va.x; acc0.y += wgt * va.y;
        acc0.z += wgt * va.z; acc0.w += wgt * va.w;
        acc1.x += wgt * vb.x; acc1.y += wgt * vb.y;
        acc1.z += wgt * vb.z; acc1.w += wgt * vb.w;
    }

    float vals[8];
    vals[0] = acc0.x * prob; vals[1] = acc0.y * prob;
    vals[2] = acc0.z * prob; vals[3] = acc0.w * prob;
    vals[4] = acc1.x * prob; vals[5] = acc1.y * prob;
    vals[6] = acc1.z * prob; vals[7] = acc1.w * prob;

    // reduce over points (lanes differing in bits 2..5)
    #pragma unroll
    for (int s = 4; s < 64; s <<= 1) {
        #pragma unroll
        for (int j = 0; j < 8; j++) vals[j] += __shfl_xor(vals[j], s);
    }

    if (lane < 8) {
        const int halfs = lane >> 2;       // 0: chans [0,16), 1: [16,32)
        const int sb = lane & 3;
        float4 v;
        if (halfs == 0) { v.x = vals[0]; v.y = vals[1]; v.z = vals[2]; v.w = vals[3]; }
        else            { v.x = vals[4]; v.y = vals[5]; v.z = vals[6]; v.w = vals[7]; }
        out[(size_t)bq * 256 + h * 32 + halfs * 16 + sb * 4 + 0] = v.x;
        out[(size_t)bq * 256 + h * 32 + halfs * 16 + sb * 4 + 1] = v.y;
        out[(size_t)bq * 256 + h * 32 + halfs * 16 + sb * 4 + 2] = v.z;
        out[(size_t)bq * 256 + h * 32 + halfs * 16 + sb * 4 + 3] = v.w;
    }
}

extern "C" void kernel_launch(void* const* d_in, const int* in_sizes, int n_in,
                              void* d_out, int out_size, void* d_ws, size_t ws_size,
                              hipStream_t stream) {
    const float* hs     = (const float*)d_in[0];   // (16,300,256)
    const float* enc    = (const float*)d_in[1];   // (16,8500,256)
    const float* refp   = (const float*)d_in[2];   // (16,300,1,4)
    // d_in[3] = spatial_shapes (int64) — static, hardcoded
    const float* w_off  = (const float*)d_in[4];   // (256,256)
    const float* b_off  = (const float*)d_in[5];   // (256,)
    const float* w_attn = (const float*)d_in[6];   // (128,256)
    const float* b_attn = (const float*)d_in[7];   // (128,)

    float* out  = (float*)d_out;            // (16,300,256)
    float* attn = out + OUT_ELEMS;          // (16,300,8,16)
    float* offlog = (float*)d_ws;           // (4800,256) fp32 = 4.9 MB

    dim3 g1(BQ_TOTAL / 64, 384 / 64);       // (75, 6)
    gemm_logits_mfma<<<g1, 256, 0, stream>>>(hs, w_off, b_off, w_attn, b_attn, offlog, attn);

    deform_sample<<<(BQ_TOTAL * N_HEADS) / 4, 256, 0, stream>>>(enc, refp, offlog, attn, out);
}